// Round 8
// baseline (57.283 us; speedup 1.0000x reference)
//
#include <hip/hip_runtime.h>

#define SGRID 14
static constexpr float INV_S = 1.0f / 14.0f;

// address-space-qualified pointer types for global_load_lds
typedef const unsigned int __attribute__((address_space(1)))* gas_ptr;
typedef unsigned int __attribute__((address_space(3)))* las_ptr;

__device__ __forceinline__ void gld_lds16(const void* g, void* l) {
    // async 16B/lane global -> LDS DMA; LDS dest = wave-uniform base + lane*16
    __builtin_amdgcn_global_load_lds((gas_ptr)g, (las_ptr)l, 16, 0, 0);
}

__device__ __forceinline__ float cell_loss(const float* p, const float* t) {
    float tconf = t[4];
    float obj   = (tconf == 1.0f) ? 1.0f : 0.0f;
    float noobj = (tconf == 0.0f) ? 1.0f : 0.0f;

    float d4 = p[4] - t[4];
    float d9 = p[9] - t[9];
    float no_object_loss = noobj * (d4 * d4 + d9 * d9);

    float class_loss = 0.0f;
    #pragma unroll
    for (int c = 10; c < 30; ++c) { float d = p[c] - t[c]; class_loss += d * d; }
    class_loss *= obj;

    float iou[2];
    #pragma unroll
    for (int b = 0; b < 2; ++b) {
        int o = b * 5;
        float pcx = p[o] * INV_S, pcy = p[o+1] * INV_S, pw = p[o+2], ph = p[o+3];
        float tcx = t[o] * INV_S, tcy = t[o+1] * INV_S, tw = t[o+2], th = t[o+3];
        float px0 = pcx - 0.5f * pw, py0 = pcy - 0.5f * ph;
        float px1 = pcx + 0.5f * pw, py1 = pcy + 0.5f * ph;
        float tx0 = tcx - 0.5f * tw, ty0 = tcy - 0.5f * th;
        float tx1 = tcx + 0.5f * tw, ty1 = tcy + 0.5f * th;
        float lx = fmaxf(px0, tx0), ly = fmaxf(py0, ty0);
        float rx = fminf(px1, tx1), ry = fminf(py1, ty1);
        float wx = fmaxf(rx - lx, 0.0f), wy = fmaxf(ry - ly, 0.0f);
        float inter = wx * wy;
        float ap = (px1 - px0) * (py1 - py0);
        float at = (tx1 - tx0) * (ty1 - ty0);
        float denom = ap + at - inter;
        iou[b] = (denom > 0.0f) ? (inter / denom) : 0.0f;
    }

    bool pick1 = (iou[0] <= iou[1]);
    float chosen = pick1 ? iou[1] : iou[0];
    int o = pick1 ? 5 : 0;

    float dx = p[o]   - t[o];
    float dy = p[o+1] - t[o+1];
    float dw = sqrtf(p[o+2]) - sqrtf(t[o+2]);
    float dh = sqrtf(p[o+3]) - sqrtf(t[o+3]);
    float reg = dx * dx + dy * dy + dw * dw + dh * dh;

    float dconf = p[o+4] - chosen;
    float contain = dconf * dconf;

    return obj * (5.0f * reg + contain) + 0.5f * no_object_loss + class_loss;
}

// Counted-vmcnt double-buffer at FULL TLP: 2-wave (128-thread) blocks,
// chunk = 64 cells = 15 KB = exactly 15 x 1KB DMA granules (per-lane source
// select handles the pred/tgt seam inside granule 7). Double-buffered
// 2 x 15.36 KB = 30.72 KB/block -> 5 blocks/CU = 10 waves/CU. Wave 0 issues
// granules 0-7, wave 1 issues 8-14; counted s_waitcnt vmcnt(8)/(7) + 2-wave
// s_barrier. Next chunk's 15 KB is always in flight during compute; the
// memory pipe never drains in the main loop.
__global__ __launch_bounds__(128) void yolo_loss_kernel(
    const float* __restrict__ pred, const float* __restrict__ tgt,
    float* __restrict__ out, int ncells, int nchunks, float invN)
{
    __shared__ float sbuf[2][3840];   // per buf: pred [0,1920), tgt [1920,3840)
    __shared__ float wpart[2];
    const int tid  = threadIdx.x;     // 0..127
    const int lane = tid & 63;
    const int wv   = tid >> 6;        // 0..1
    float sum = 0.0f;

    const int stride = gridDim.x;
    int chunk = blockIdx.x;
    int buf = 0;

    auto stage = [&](int c, int b) {
        // wave 0: granules 0..7, wave 1: granules 8..14
        const int g0 = (wv == 0) ? 0 : 8;
        const int gn = (wv == 0) ? 8 : 7;
        const float* pbase = pred + (size_t)c * 1920;
        const float* tbase = tgt  + (size_t)c * 1920;
        #pragma unroll 8
        for (int gi = 0; gi < gn; ++gi) {
            int g = g0 + gi;
            int w = g * 256 + lane * 4;                  // word offset 0..3836
            const float* src = (w < 1920) ? (pbase + w) : (tbase + (w - 1920));
            gld_lds16((const void*)src, (void*)&sbuf[b][g * 256]);
        }
    };

    if (chunk < nchunks) stage(chunk, 0);

    while (chunk < nchunks) {
        int next = chunk + stride;
        if (next < nchunks) {
            stage(next, buf ^ 1);
            // per-wave FIFO: wait until only the just-issued remain
            if (wv == 0) asm volatile("s_waitcnt vmcnt(8)" ::: "memory");
            else         asm volatile("s_waitcnt vmcnt(7)" ::: "memory");
        } else {
            asm volatile("s_waitcnt vmcnt(0)" ::: "memory");
        }
        __builtin_amdgcn_s_barrier();      // both waves' granules certified
        asm volatile("" ::: "memory");

        if (lane < 32) {
            int cell = wv * 32 + lane;     // 0..63
            const float* base = &sbuf[buf][0];
            const float2* cp2 = (const float2*)(base + cell * 30);
            const float2* ct2 = (const float2*)(base + 1920 + cell * 30);
            float p[30], t[30];
            #pragma unroll
            for (int j = 0; j < 15; ++j) { float2 v = cp2[j]; p[2*j] = v.x; p[2*j+1] = v.y; }
            #pragma unroll
            for (int j = 0; j < 15; ++j) { float2 v = ct2[j]; t[2*j] = v.x; t[2*j+1] = v.y; }
            sum += cell_loss(p, t);
        }

        asm volatile("" ::: "memory");
        __builtin_amdgcn_s_barrier();      // partner done reading buf -> safe to DMA

        buf ^= 1;
        chunk = next;
    }

    // remainder cells (ncells % 64) — direct global path, block 0 only
    int rem = ncells - nchunks * 64;
    if (rem > 0 && blockIdx.x == 0 && tid < rem) {
        int cell = nchunks * 64 + tid;
        const float2* p2 = (const float2*)(pred + (size_t)cell * 30);
        const float2* t2 = (const float2*)(tgt  + (size_t)cell * 30);
        float p[30], t[30];
        #pragma unroll
        for (int j = 0; j < 15; ++j) { float2 v = p2[j]; p[2*j] = v.x; p[2*j+1] = v.y; }
        #pragma unroll
        for (int j = 0; j < 15; ++j) { float2 v = t2[j]; t[2*j] = v.x; t[2*j+1] = v.y; }
        sum += cell_loss(p, t);
    }

    #pragma unroll
    for (int off = 16; off > 0; off >>= 1) sum += __shfl_down(sum, off, 64);
    if (lane == 0) wpart[wv] = sum;
    __syncthreads();
    if (tid == 0) atomicAdd(out, (wpart[0] + wpart[1]) * invN);
}

extern "C" void kernel_launch(void* const* d_in, const int* in_sizes, int n_in,
                              void* d_out, int out_size, void* d_ws, size_t ws_size,
                              hipStream_t stream) {
    const float* pred = (const float*)d_in[0];
    const float* tgt  = (const float*)d_in[1];
    float* out = (float*)d_out;

    int ncells  = in_sizes[0] / 30;               // N * S * S
    int N       = ncells / (SGRID * SGRID);
    float invN  = 1.0f / (float)N;
    int nchunks = ncells / 64;

    hipMemsetAsync(out, 0, sizeof(float) * (out_size > 0 ? out_size : 1), stream);

    // 30.72 KB LDS -> 5 blocks/CU; 5 x 256 = 1280 resident blocks
    int blocks = nchunks < 1 ? 1 : (nchunks < 1280 ? nchunks : 1280);
    yolo_loss_kernel<<<blocks, 128, 0, stream>>>(pred, tgt, out, ncells, nchunks, invN);
}

// Round 9
// 42.314 us; speedup vs baseline: 1.3538x; 1.3538x over previous
//
#include <hip/hip_runtime.h>

#define SGRID 14
static constexpr float INV_S = 1.0f / 14.0f;

__device__ __forceinline__ float cell_loss(const float* p, const float* t) {
    float tconf = t[4];
    float obj   = (tconf == 1.0f) ? 1.0f : 0.0f;
    float noobj = (tconf == 0.0f) ? 1.0f : 0.0f;

    float d4 = p[4] - t[4];
    float d9 = p[9] - t[9];
    float no_object_loss = noobj * (d4 * d4 + d9 * d9);

    float class_loss = 0.0f;
    #pragma unroll
    for (int c = 10; c < 30; ++c) { float d = p[c] - t[c]; class_loss += d * d; }
    class_loss *= obj;

    float iou[2];
    #pragma unroll
    for (int b = 0; b < 2; ++b) {
        int o = b * 5;
        float pcx = p[o] * INV_S, pcy = p[o+1] * INV_S, pw = p[o+2], ph = p[o+3];
        float tcx = t[o] * INV_S, tcy = t[o+1] * INV_S, tw = t[o+2], th = t[o+3];
        float px0 = pcx - 0.5f * pw, py0 = pcy - 0.5f * ph;
        float px1 = pcx + 0.5f * pw, py1 = pcy + 0.5f * ph;
        float tx0 = tcx - 0.5f * tw, ty0 = tcy - 0.5f * th;
        float tx1 = tcx + 0.5f * tw, ty1 = tcy + 0.5f * th;
        float lx = fmaxf(px0, tx0), ly = fmaxf(py0, ty0);
        float rx = fminf(px1, tx1), ry = fminf(py1, ty1);
        float wx = fmaxf(rx - lx, 0.0f), wy = fmaxf(ry - ly, 0.0f);
        float inter = wx * wy;
        float ap = (px1 - px0) * (py1 - py0);
        float at = (tx1 - tx0) * (ty1 - ty0);
        float denom = ap + at - inter;
        iou[b] = (denom > 0.0f) ? (inter / denom) : 0.0f;
    }

    bool pick1 = (iou[0] <= iou[1]);
    float chosen = pick1 ? iou[1] : iou[0];
    int o = pick1 ? 5 : 0;

    float dx = p[o]   - t[o];
    float dy = p[o+1] - t[o+1];
    float dw = sqrtf(p[o+2]) - sqrtf(t[o+2]);
    float dh = sqrtf(p[o+3]) - sqrtf(t[o+3]);
    float reg = dx * dx + dy * dy + dw * dw + dh * dh;

    float dconf = p[o+4] - chosen;
    float contain = dconf * dconf;

    return obj * (5.0f * reg + contain) + 0.5f * no_object_loss + class_loss;
}

// R4 structure, staging mechanism swapped: REG-STAGED transpose instead of
// the global_load_lds DMA engine. 4-wave (256-thread) blocks, chunk = 256
// cells, single 61.44 KB buffer -> 2 blocks/CU = 8 waves/CU. Each thread:
// 30 coalesced global_load_dwordx2 (15 KB/wave in flight; 120 KB/CU) then
// 30 ds_write_b64; register deps give per-load counted vmcnt for free.
// Compute identical to R4.
__global__ __launch_bounds__(256) void yolo_loss_kernel(
    const float* __restrict__ pred, const float* __restrict__ tgt,
    float* __restrict__ out, int ncells, int nchunks, float invN)
{
    __shared__ float sbuf[15360];     // 61440 B: pred [0,7680), tgt [7680,15360)
    __shared__ float wpart[4];
    const int tid  = threadIdx.x;     // 0..255
    const int lane = tid & 63;
    const int wv   = tid >> 6;        // 0..3
    float sum = 0.0f;

    for (int chunk = blockIdx.x; chunk < nchunks; chunk += gridDim.x) {
        const float2* p2 = (const float2*)(pred + (size_t)chunk * 7680);
        const float2* t2 = (const float2*)(tgt  + (size_t)chunk * 7680);

        // coalesced register staging: 30 dwordx2 loads, full MLP
        float2 vp[15], vt[15];
        #pragma unroll
        for (int k = 0; k < 15; ++k) vp[k] = p2[tid + k * 256];
        #pragma unroll
        for (int k = 0; k < 15; ++k) vt[k] = t2[tid + k * 256];

        float2* sp = (float2*)sbuf;
        float2* st = (float2*)(sbuf + 7680);
        #pragma unroll
        for (int k = 0; k < 15; ++k) sp[tid + k * 256] = vp[k];
        #pragma unroll
        for (int k = 0; k < 15; ++k) st[tid + k * 256] = vt[k];

        __syncthreads();   // ds_writes drained; buffer valid

        {
            const float2* cp2 = (const float2*)(sbuf + tid * 30);
            const float2* ct2 = (const float2*)(sbuf + 7680 + tid * 30);
            float p[30], t[30];
            #pragma unroll
            for (int j = 0; j < 15; ++j) { float2 v = cp2[j]; p[2*j] = v.x; p[2*j+1] = v.y; }
            #pragma unroll
            for (int j = 0; j < 15; ++j) { float2 v = ct2[j]; t[2*j] = v.x; t[2*j+1] = v.y; }
            sum += cell_loss(p, t);
        }
        __syncthreads();   // buffer safe to overwrite next iteration
    }

    // remainder cells (ncells % 256) — direct global path, block 0 only
    int rem = ncells - nchunks * 256;
    if (rem > 0 && blockIdx.x == 0 && tid < rem) {
        int cell = nchunks * 256 + tid;
        const float2* p2 = (const float2*)(pred + (size_t)cell * 30);
        const float2* t2 = (const float2*)(tgt  + (size_t)cell * 30);
        float p[30], t[30];
        #pragma unroll
        for (int j = 0; j < 15; ++j) { float2 v = p2[j]; p[2*j] = v.x; p[2*j+1] = v.y; }
        #pragma unroll
        for (int j = 0; j < 15; ++j) { float2 v = t2[j]; t[2*j] = v.x; t[2*j+1] = v.y; }
        sum += cell_loss(p, t);
    }

    #pragma unroll
    for (int off = 32; off > 0; off >>= 1) sum += __shfl_down(sum, off, 64);
    if (lane == 0) wpart[wv] = sum;
    __syncthreads();
    if (tid == 0)
        atomicAdd(out, (wpart[0] + wpart[1] + wpart[2] + wpart[3]) * invN);
}

extern "C" void kernel_launch(void* const* d_in, const int* in_sizes, int n_in,
                              void* d_out, int out_size, void* d_ws, size_t ws_size,
                              hipStream_t stream) {
    const float* pred = (const float*)d_in[0];
    const float* tgt  = (const float*)d_in[1];
    float* out = (float*)d_out;

    int ncells  = in_sizes[0] / 30;               // N * S * S
    int N       = ncells / (SGRID * SGRID);
    float invN  = 1.0f / (float)N;
    int nchunks = ncells / 256;

    hipMemsetAsync(out, 0, sizeof(float) * (out_size > 0 ? out_size : 1), stream);

    // 61.44 KB LDS -> 2 blocks/CU; 512 resident blocks
    int blocks = nchunks < 1 ? 1 : (nchunks < 512 ? nchunks : 512);
    yolo_loss_kernel<<<blocks, 256, 0, stream>>>(pred, tgt, out, ncells, nchunks, invN);
}